// Round 10
// baseline (156.904 us; speedup 1.0000x reference)
//
#include <hip/hip_runtime.h>
#include <hip/hip_bf16.h>
#include <math.h>

#define N_NODES 100000
#define N_PAD   100032      // 1563 * 64, multiple of 32
#define F_IN    100
#define HID     128
#define NCLS    64
#define KA      256         // K for layer-1: [agg(100)|0(28)|x(100)|0(28)]
#define NTILES  (N_PAD / 32)
#define GRID_F  512         // one launch wave at 2 blocks/CU
#define TILE_Q  (NTILES / GRID_F)   // 6
#define TILE_R  (NTILES % GRID_F)   // 54

// merged prep kernel block ranges
#define PREPX_CHUNKS  (N_PAD * 16)                        // 8-col chunks, Xc cols 0..127
#define PREPX_BLOCKS  ((PREPX_CHUNKS + 255) / 256)        // 6252
#define PREPW_BLOCKS  64
#define ROWPTR_BLOCKS ((N_NODES + 1 + 255) / 256)         // 391
#define PREP_GRID     (PREPX_BLOCKS + PREPW_BLOCKS + ROWPTR_BLOCKS)

typedef __attribute__((ext_vector_type(8))) short bf16x8;
typedef __attribute__((ext_vector_type(4))) float f32x4;
typedef __attribute__((ext_vector_type(8))) unsigned short ushort8;

// Pin a loaded value in VGPRs (r2 lesson: compiler otherwise re-loads W
// from global before every MFMA).
#define KEEP(x) asm volatile("" : "+v"(x))

static __device__ __forceinline__ ushort f2bf(float f) {
    union { float f; unsigned u; } v; v.f = f;
    unsigned r = (v.u + 0x7FFFu + ((v.u >> 16) & 1u)) >> 16;
    return (ushort)r;
}
static __device__ __forceinline__ float bflo(unsigned u) {
    union { unsigned u; float f; } v; v.u = u << 16; return v.f;
}
static __device__ __forceinline__ float bfhi(unsigned u) {
    union { unsigned u; float f; } v; v.u = u & 0xFFFF0000u; return v.f;
}
static __device__ __forceinline__ float bf2f(ushort u) {
    union { unsigned u; float f; } v; v.u = ((unsigned)u) << 16; return v.f;
}

// ---- merged prep: x->Xc bf16 staging | W/b prep | row_ptr ------------------
__global__ __launch_bounds__(256) void prep_all_kernel(
    const float* __restrict__ x,
    const int* __restrict__ rows, int n_edges,
    const float* __restrict__ Wl1, const float* __restrict__ bl1,
    const float* __restrict__ Wr1, const float* __restrict__ br1,
    const float* __restrict__ Wl2, const float* __restrict__ bl2,
    const float* __restrict__ Wr2, const float* __restrict__ br2,
    ushort* __restrict__ Xc, ushort* __restrict__ W1, ushort* __restrict__ W2,
    float* __restrict__ b1, float* __restrict__ b2,
    int* __restrict__ row_ptr) {
    int b = blockIdx.x;
    if (b < PREPX_BLOCKS) {
        // ---- prep_x: Xc[node][0:128] = [x bf16 (100) | 0 (28)], compact ----
        // 25.6 MB footprint (vs 51.2 MB padded Abf): gather + staging source.
        int i = b * 256 + threadIdx.x;               // over N_PAD * 16
        if (i >= PREPX_CHUNKS) return;
        int node = i >> 4;
        int c8 = i & 15;
        int col = c8 * 8;                            // 0..120, step 8
        ushort8 o = (ushort8){0, 0, 0, 0, 0, 0, 0, 0};
        if (node < N_NODES && col < F_IN) {
            const float* xp = x + (size_t)node * F_IN + col;
            if (col <= 88) {                         // fully inside x
                float4 v0 = *(const float4*)xp;
                float4 v1 = *(const float4*)(xp + 4);
                o = (ushort8){f2bf(v0.x), f2bf(v0.y), f2bf(v0.z), f2bf(v0.w),
                              f2bf(v1.x), f2bf(v1.y), f2bf(v1.z), f2bf(v1.w)};
            } else {                                 // col==96: feats 96..99
                float4 v0 = *(const float4*)xp;
                o = (ushort8){f2bf(v0.x), f2bf(v0.y), f2bf(v0.z), f2bf(v0.w),
                              0, 0, 0, 0};
            }
        }
        *(ushort8*)(Xc + (size_t)node * 128 + col) = o;
        return;
    }
    b -= PREPX_BLOCKS;
    if (b < PREPW_BLOCKS) {
        // ---- prep_w: weights/bias, bf16, with row interleave ----
        // storage row s -> jorig = (s & ~31) + 2*(s&15) + ((s>>4)&1)
        int tid = b * 256 + threadIdx.x;
        int stride = PREPW_BLOCKS * 256;
        for (int i = tid; i < HID * KA; i += stride) {   // W1: [128][256]
            int s = i >> 8, k = i & 255;
            int j = (s & ~31) + 2 * (s & 15) + ((s >> 4) & 1);
            float v = 0.f;
            if (k < F_IN) v = Wl1[j * F_IN + k];
            else if (k >= 128 && k < 128 + F_IN) v = Wr1[j * F_IN + (k - 128)];
            W1[i] = f2bf(v);
        }
        for (int i = tid; i < HID * HID; i += stride) {  // W2: [128][128]
            int s = i >> 7, k = i & 127;
            int j = (s & ~31) + 2 * (s & 15) + ((s >> 4) & 1);
            float v = (j < NCLS) ? Wl2[j * HID + k] : Wr2[(j - NCLS) * HID + k];
            W2[i] = f2bf(v);
        }
        if (tid < HID) b1[tid] = bl1[tid] + br1[tid];
        if (tid < NCLS) b2[tid] = bl2[tid] + br2[tid];
        return;
    }
    b -= PREPW_BLOCKS;
    {
        // ---- row_ptr via binary search over sorted rows ----
        int i = b * 256 + threadIdx.x;
        if (i > N_NODES) return;
        int lo = 0, hi = n_edges;
        while (lo < hi) {
            int mid = (lo + hi) >> 1;
            if (rows[mid] < i) lo = mid + 1; else hi = mid;
        }
        row_ptr[i] = lo;
    }
}

// ---- per-tile agg gather (fused spmm1): wave w aggregates tile rows w*8..+7,
// writing agg (bf16, bytes 0-199) + zeros (200-255) straight into the
// XOR-swizzled A-staging LDS. Same proven 8-deep gather inner loop as the
// standalone spmm1 (r3-r6: at the line-service-rate wall). Lanes 0-49: 2
// feats each; lanes 50-63: pad zeros. row_ptr preloaded lane-parallel.
static __device__ __forceinline__ void gather_tile(
    const float* __restrict__ vals, const int* __restrict__ cols,
    const int* __restrict__ row_ptr, const ushort* __restrict__ Xc,
    char* dst, int nbase, int w, int lane) {
    int rbase = nbase + w * 8;
    int idx = rbase + (lane < 9 ? lane : 8);
    if (idx > N_NODES) idx = N_NODES;                // pad rows -> s==e -> 0
    int rpv = row_ptr[idx];
    const ushort* xb = Xc + lane * 2;
#pragma unroll 1
    for (int k = 0; k < 8; ++k) {
        int nl = w * 8 + k;
        int dstrow = nl * 512;
        int sw = nl & 7;
        int s = __builtin_amdgcn_readfirstlane(__shfl(rpv, k));
        int e = __builtin_amdgcn_readfirstlane(__shfl(rpv, k + 1));
        if (lane < 50) {
            float accx[4] = {0.f, 0.f, 0.f, 0.f};
            float accy[4] = {0.f, 0.f, 0.f, 0.f};
            int i = s;
            for (; i + 8 <= e; i += 8) {
                float v[8]; unsigned u[8];
#pragma unroll
                for (int q = 0; q < 8; ++q) {
                    v[q] = vals[i + q];
                    u[q] = *(const unsigned*)(xb + (size_t)cols[i + q] * 128);
                }
#pragma unroll
                for (int q = 0; q < 8; ++q) {
                    accx[q & 3] += v[q] * bflo(u[q]);
                    accy[q & 3] += v[q] * bfhi(u[q]);
                }
            }
            if (i + 4 <= e) {
                float v[4]; unsigned u[4];
#pragma unroll
                for (int q = 0; q < 4; ++q) {
                    v[q] = vals[i + q];
                    u[q] = *(const unsigned*)(xb + (size_t)cols[i + q] * 128);
                }
#pragma unroll
                for (int q = 0; q < 4; ++q) {
                    accx[q] += v[q] * bflo(u[q]);
                    accy[q] += v[q] * bfhi(u[q]);
                }
                i += 4;
            }
            for (; i < e; ++i) {
                float v = vals[i];
                unsigned u = *(const unsigned*)(xb + (size_t)cols[i] * 128);
                accx[0] += v * bflo(u);
                accy[0] += v * bfhi(u);
            }
            float ax = (accx[0] + accx[1]) + (accx[2] + accx[3]);
            float ay = (accy[0] + accy[1]) + (accy[2] + accy[3]);
            unsigned o = ((unsigned)f2bf(ay) << 16) | (unsigned)f2bf(ax);
            int b = lane * 4;                        // bytes 0..199
            *(unsigned*)(dst + dstrow + (((b >> 4) ^ sw) << 4) + (b & 15)) = o;
        } else {
            int b = 200 + (lane - 50) * 4;           // bytes 200..255 zeroed
            *(unsigned*)(dst + dstrow + (((b >> 4) ^ sw) << 4) + (b & 15)) = 0u;
        }
    }
}

// ---- Fused SpMM1+GEMM: gather-in-kernel, LDS-staged A, KEEP-pinned W -------
// spmm1->gemm is node-local, so each block aggregates its own tile rows and
// feeds them straight to the MFMAs: the serial spmm1+gemm slot collapses to
// ~the gather wall; agg never round-trips through global (saves 22 MB write
// + re-read + one launch). Body skeleton is the r6/r9 proven equilibrium.
__global__ __launch_bounds__(256, 2) void gemm_fused_kernel(
    const ushort* __restrict__ Xc, const ushort* __restrict__ W1,
    const ushort* __restrict__ W2, const float* __restrict__ b1,
    const float* __restrict__ vals, const int* __restrict__ cols,
    const int* __restrict__ row_ptr,
    ushort* __restrict__ t, ushort* __restrict__ rb) {
    __shared__ char Ald[2][16384];                   // dbuf: 32 nodes x 256 bf16
    __shared__ char h_lds[2][8192];                  // dbuf: 32 nodes x 128 bf16
    __shared__ __align__(16) float part[2][32][4];   // [buf][node][wave] L1 partials
    int lane = threadIdx.x & 63;
    int w = threadIdx.x >> 6;
    int m = lane & 15, g = lane >> 4;

    int bb = blockIdx.x;
    int t0 = bb * TILE_Q + (bb < TILE_R ? bb : TILE_R);
    int ntl = TILE_Q + (bb < TILE_R ? 1 : 0);        // balanced 6-7 tiles

    // ---- W frags: loaded once, pinned ----
    bf16x8 wf1[2][8];
    bf16x8 wf2[2][4];
#pragma unroll
    for (int o = 0; o < 2; ++o) {
        const ushort* wrow = W1 + (size_t)(w * 32 + o * 16 + m) * KA + g * 8;
#pragma unroll
        for (int kb = 0; kb < 8; ++kb) wf1[o][kb] = *(const bf16x8*)(wrow + kb * 32);
    }
#pragma unroll
    for (int o = 0; o < 2; ++o) {
        const ushort* wrow = W2 + (size_t)(w * 32 + o * 16 + m) * HID + g * 8;
#pragma unroll
        for (int kb = 0; kb < 4; ++kb) wf2[o][kb] = *(const bf16x8*)(wrow + kb * 32);
    }
#pragma unroll
    for (int o = 0; o < 2; ++o) {
#pragma unroll
        for (int kb = 0; kb < 8; ++kb) KEEP(wf1[o][kb]);
#pragma unroll
        for (int kb = 0; kb < 4; ++kb) KEEP(wf2[o][kb]);
    }
    float bias0 = b1[w * 32 + 2 * m + 0];
    float bias1 = b1[w * 32 + 2 * m + 1];

    // ---- prologue: stage tile t0 (x-part from Xc + gathered agg) ----
    bf16x8 st[2];
#pragma unroll
    for (int i2 = 0; i2 < 2; ++i2) {
        int idx = (w * 2 + i2) * 64 + lane;          // 0..511 (16B x-chunks)
        int nl = idx >> 4, c16 = idx & 15;
        st[i2] = *(const bf16x8*)(Xc + (size_t)(t0 * 32 + nl) * 128 + c16 * 8);
    }
#pragma unroll
    for (int i2 = 0; i2 < 2; ++i2) {
        int idx = (w * 2 + i2) * 64 + lane;
        int nl = idx >> 4, c16 = idx & 15;
        int dst = nl * 512 + 256 + ((c16 ^ (nl & 7)) << 4);
        *(bf16x8*)(&Ald[0][0] + dst) = st[i2];
    }
    gather_tile(vals, cols, row_ptr, Xc, &Ald[0][0], t0 * 32, w, lane);
    __syncthreads();

    for (int j = 0; ; ) {
        int buf = j & 1;
        int base = (t0 + j) * 32;
        bool last = (j + 1 >= ntl);
        int tn = t0 + j + 1;

        // ---- issue next tile's x-part loads (fly under phase 1) ----
        if (!last) {
#pragma unroll
            for (int i2 = 0; i2 < 2; ++i2) {
                int idx = (w * 2 + i2) * 64 + lane;
                int nl = idx >> 4, c16 = idx & 15;
                st[i2] = *(const bf16x8*)(Xc + (size_t)(tn * 32 + nl) * 128 + c16 * 8);
            }
        }

        // ---- phase 1: layer-1 MFMAs, A from LDS (swizzled reads) ----
        f32x4 acc1[2][2];
#pragma unroll
        for (int mt = 0; mt < 2; ++mt)
#pragma unroll
            for (int o = 0; o < 2; ++o) acc1[mt][o] = (f32x4){0.f, 0.f, 0.f, 0.f};
#pragma unroll
        for (int mt = 0; mt < 2; ++mt) {
            int nl = mt * 16 + m;
            int rowb = nl * 512;
            int swz = (nl & 7) << 4;
#pragma unroll
            for (int kb = 0; kb < 8; ++kb) {
                bf16x8 a = *(const bf16x8*)(&Ald[buf][0] + rowb + ((((g + 4 * kb)) << 4) ^ swz));
                acc1[mt][0] = __builtin_amdgcn_mfma_f32_16x16x32_bf16(a, wf1[0][kb], acc1[mt][0], 0, 0, 0);
                acc1[mt][1] = __builtin_amdgcn_mfma_f32_16x16x32_bf16(a, wf1[1][kb], acc1[mt][1], 0, 0, 0);
            }
        }

        // ---- bias; relu(h) -> h_lds (UN-normalized); partial L1 ----
        float sr[2][4];
#pragma unroll
        for (int mt = 0; mt < 2; ++mt)
#pragma unroll
            for (int r = 0; r < 4; ++r) {
                acc1[mt][0][r] += bias0;
                acc1[mt][1][r] += bias1;
                sr[mt][r] = fabsf(acc1[mt][0][r]) + fabsf(acc1[mt][1][r]);
                int nl = mt * 16 + g * 4 + r;
                unsigned lo = f2bf(fmaxf(acc1[mt][0][r], 0.f));
                unsigned hi = f2bf(fmaxf(acc1[mt][1][r], 0.f));
                int off = (nl * 256 + w * 64 + m * 4) ^ ((nl & 7) << 4);
                *(unsigned*)(&h_lds[buf][0] + off) = (hi << 16) | lo;
            }
#pragma unroll
        for (int off = 1; off < 16; off <<= 1)
#pragma unroll
            for (int mt = 0; mt < 2; ++mt)
#pragma unroll
                for (int r = 0; r < 4; ++r) sr[mt][r] += __shfl_xor(sr[mt][r], off);
        if (m == 0) {
#pragma unroll
            for (int mt = 0; mt < 2; ++mt)
#pragma unroll
                for (int r = 0; r < 4; ++r) part[buf][mt * 16 + g * 4 + r][w] = sr[mt][r];
        }

        // ---- next tile's A into Ald[buf^1]: x-part writes + agg gather ----
        // (acc1 dead; Ald[buf^1] was last read in iteration j-1's phase 1,
        //  which every wave completed before iteration j-1's barrier)
        if (!last) {
#pragma unroll
            for (int i2 = 0; i2 < 2; ++i2) {
                int idx = (w * 2 + i2) * 64 + lane;
                int nl = idx >> 4, c16 = idx & 15;
                int dst = nl * 512 + 256 + ((c16 ^ (nl & 7)) << 4);
                *(bf16x8*)(&Ald[buf ^ 1][0] + dst) = st[i2];
            }
            gather_tile(vals, cols, row_ptr, Xc, &Ald[buf ^ 1][0], tn * 32, w, lane);
        }
        __syncthreads();        // single barrier/tile: h+part+next-A visible

        // ---- phase 2: layer-2 MFMAs from LDS relu(h) ----
        f32x4 acc2[2][2];
#pragma unroll
        for (int mt = 0; mt < 2; ++mt)
#pragma unroll
            for (int o = 0; o < 2; ++o) acc2[mt][o] = (f32x4){0.f, 0.f, 0.f, 0.f};
#pragma unroll
        for (int mt = 0; mt < 2; ++mt) {
            int nl = mt * 16 + m;
            bf16x8 a[4];
#pragma unroll
            for (int kb = 0; kb < 4; ++kb) {
                int off = (nl * 256 + g * 16 + kb * 64) ^ ((nl & 7) << 4);
                a[kb] = *(const bf16x8*)(&h_lds[buf][0] + off);
            }
#pragma unroll
            for (int kb = 0; kb < 4; ++kb) {
                acc2[mt][0] = __builtin_amdgcn_mfma_f32_16x16x32_bf16(a[kb], wf2[0][kb], acc2[mt][0], 0, 0, 0);
                acc2[mt][1] = __builtin_amdgcn_mfma_f32_16x16x32_bf16(a[kb], wf2[1][kb], acc2[mt][1], 0, 0, 0);
            }
        }

        // ---- epilogue: deferred 1/||h||_1, packed dword stores ----
        ushort* obuf = (w < 2) ? t : rb;
        int colb = (w & 1) * 32 + 2 * m;
#pragma unroll
        for (int mt = 0; mt < 2; ++mt)
#pragma unroll
            for (int r = 0; r < 4; ++r) {
                int nl = mt * 16 + g * 4 + r;
                int node = base + nl;
                float4 p = *(const float4*)&part[buf][nl][0];
                float inv = 1.f / fmaxf((p.x + p.y) + (p.z + p.w), 1e-12f);
                unsigned lo = f2bf(acc2[mt][0][r] * inv);
                unsigned hi = f2bf(acc2[mt][1][r] * inv);
                *(unsigned*)(obuf + (size_t)node * NCLS + colb) = (hi << 16) | lo;
            }

        if (last) break;
        ++j;
    }
}

// ---- SpMM 2 on t (bf16, D=64) + rb + bias, fused log_softmax ---------------
// one wave per node, 8-deep gather pipeline (structural roofline: 1 coalesced
// line/edge). rb/b2 tail loads hoisted ahead of the edge loop (KEEP, r8: -2.4us).
__global__ __launch_bounds__(256) void spmm2_kernel(
    const float* __restrict__ vals, const int* __restrict__ cols,
    const int* __restrict__ row_ptr, const ushort* __restrict__ t,
    const ushort* __restrict__ rb, const float* __restrict__ b2,
    float* __restrict__ out) {
    int node = blockIdx.x * 4 + (threadIdx.x >> 6);
    if (node >= N_NODES) return;
    int lane = threadIdx.x & 63;
    int s = __builtin_amdgcn_readfirstlane(row_ptr[node]);
    int e = __builtin_amdgcn_readfirstlane(row_ptr[node + 1]);

    // hoisted epilogue loads (issued before the gather loop)
    unsigned rbv = rb[(size_t)node * NCLS + lane];
    float b2v = b2[lane];
    KEEP(rbv);
    KEEP(b2v);

    float a4[4] = {0.f, 0.f, 0.f, 0.f};
    int i = s;
    for (; i + 8 <= e; i += 8) {
        float v[8], tv[8];
#pragma unroll
        for (int q = 0; q < 8; ++q) {
            v[q] = vals[i + q];
            tv[q] = bf2f(t[(size_t)cols[i + q] * NCLS + lane]);
        }
#pragma unroll
        for (int q = 0; q < 8; ++q) a4[q & 3] += v[q] * tv[q];
    }
    if (i + 4 <= e) {
        float v[4], tv[4];
#pragma unroll
        for (int q = 0; q < 4; ++q) {
            v[q] = vals[i + q];
            tv[q] = bf2f(t[(size_t)cols[i + q] * NCLS + lane]);
        }
#pragma unroll
        for (int q = 0; q < 4; ++q) a4[q] += v[q] * tv[q];
        i += 4;
    }
    for (; i < e; ++i) a4[0] += vals[i] * bf2f(t[(size_t)cols[i] * NCLS + lane]);
    float acc = (a4[0] + a4[1]) + (a4[2] + a4[3]);
    acc += bf2f((ushort)rbv) + b2v;

    float mx = acc;
#pragma unroll
    for (int off = 32; off; off >>= 1) mx = fmaxf(mx, __shfl_xor(mx, off));
    float ex = expf(acc - mx);
    float ss = ex;
#pragma unroll
    for (int off = 32; off; off >>= 1) ss += __shfl_xor(ss, off);
    out[(size_t)node * NCLS + lane] = acc - mx - logf(ss);
}

extern "C" void kernel_launch(void* const* d_in, const int* in_sizes, int n_in,
                              void* d_out, int out_size, void* d_ws, size_t ws_size,
                              hipStream_t stream) {
    const float* x         = (const float*)d_in[0];
    const float* edge_vals = (const float*)d_in[1];
    const float* Wl1       = (const float*)d_in[2];
    const float* bl1       = (const float*)d_in[3];
    const float* Wr1       = (const float*)d_in[4];
    const float* br1       = (const float*)d_in[5];
    const float* Wl2       = (const float*)d_in[6];
    const float* bl2       = (const float*)d_in[7];
    const float* Wr2       = (const float*)d_in[8];
    const float* br2       = (const float*)d_in[9];
    const int* edge_rows   = (const int*)d_in[10];
    const int* edge_cols   = (const int*)d_in[11];
    float* out = (float*)d_out;

    int n_edges = in_sizes[1];

    char* ws = (char*)d_ws;
    int*    row_ptr = (int*)(ws + 0);                        // 400 KB
    ushort* Xc      = (ushort*)(ws + (1u << 20));            // N_PAD*128*2 = 25.6 MB
    ushort* t_buf   = (ushort*)(ws + 52264960u);             // N_PAD*64*2 = 12.8 MB
    ushort* r_buf   = (ushort*)(ws + 65069056u);             // 12.8 MB
    ushort* W1      = (ushort*)(ws + 77873152u);             // 64 KB
    ushort* W2      = (ushort*)(ws + 77938688u);             // 32 KB
    float*  b1      = (float*)(ws + 77971456u);              // 512 B
    float*  b2      = (float*)(ws + 77971968u);              // 256 B

    prep_all_kernel<<<PREP_GRID, 256, 0, stream>>>(
        x, edge_rows, n_edges, Wl1, bl1, Wr1, br1, Wl2, bl2, Wr2, br2,
        Xc, W1, W2, b1, b2, row_ptr);
    gemm_fused_kernel<<<GRID_F, 256, 0, stream>>>(
        Xc, W1, W2, b1, edge_vals, edge_cols, row_ptr, t_buf, r_buf);
    spmm2_kernel<<<(N_NODES + 3) / 4, 256, 0, stream>>>(
        edge_vals, edge_cols, row_ptr, t_buf, r_buf, b2, out);
}

// Round 11
// 121.620 us; speedup vs baseline: 1.2901x; 1.2901x over previous
//
#include <hip/hip_runtime.h>
#include <hip/hip_bf16.h>
#include <math.h>

#define N_NODES 100000
#define N_PAD   100032      // 1563 * 64, multiple of 32
#define F_IN    100
#define HID     128
#define NCLS    64
#define KA      256         // padded K for layer-1 A rows: [agg(100)|0|x(100)|0]
#define XOFF    128         // x part starts at element 128
#define NTILES  (N_PAD / 32)
#define GRID_F  512         // one full launch wave at 2 blocks/CU; 6-7 tiles/block
#define TILE_Q  (NTILES / GRID_F)   // 6
#define TILE_R  (NTILES % GRID_F)   // 30

// merged prep kernel block ranges
#define PREPX_CHUNKS  (N_PAD * 20)                        // 8-col chunks, cols 96..255
#define PREPX_BLOCKS  ((PREPX_CHUNKS + 255) / 256)        // 7815
#define PADZ_BLOCKS   4                                   // 32 rows x 32 chunks
#define PREPW_BLOCKS  64
#define ROWPTR_BLOCKS ((N_NODES + 1 + 255) / 256)         // 391
#define PREP_GRID     (PREPX_BLOCKS + PADZ_BLOCKS + PREPW_BLOCKS + ROWPTR_BLOCKS)

typedef __attribute__((ext_vector_type(8))) short bf16x8;
typedef __attribute__((ext_vector_type(4))) float f32x4;
typedef __attribute__((ext_vector_type(8))) unsigned short ushort8;

// Pin a loaded value in VGPRs: asm "modifies" it, so the compiler can neither
// rematerialize it from memory nor sink the load to the use point.
#define KEEP(x) asm volatile("" : "+v"(x))

static __device__ __forceinline__ ushort f2bf(float f) {
    union { float f; unsigned u; } v; v.f = f;
    unsigned r = (v.u + 0x7FFFu + ((v.u >> 16) & 1u)) >> 16;
    return (ushort)r;
}
static __device__ __forceinline__ float bflo(unsigned u) {
    union { unsigned u; float f; } v; v.u = u << 16; return v.f;
}
static __device__ __forceinline__ float bfhi(unsigned u) {
    union { unsigned u; float f; } v; v.u = u & 0xFFFF0000u; return v.f;
}
static __device__ __forceinline__ float bf2f(ushort u) {
    union { unsigned u; float f; } v; v.u = ((unsigned)u) << 16; return v.f;
}

// ---- merged prep: x->bf16 staging | pad-row zero | W/b prep | row_ptr ------
// Four independent jobs partitioned by blockIdx range.
__global__ __launch_bounds__(256) void prep_all_kernel(
    const float* __restrict__ x,
    const int* __restrict__ rows, int n_edges,
    const float* __restrict__ Wl1, const float* __restrict__ bl1,
    const float* __restrict__ Wr1, const float* __restrict__ br1,
    const float* __restrict__ Wl2, const float* __restrict__ bl2,
    const float* __restrict__ Wr2, const float* __restrict__ br2,
    ushort* __restrict__ Abf, ushort* __restrict__ W1, ushort* __restrict__ W2,
    float* __restrict__ b1, float* __restrict__ b2,
    int* __restrict__ row_ptr) {
    int b = blockIdx.x;
    if (b < PREPX_BLOCKS) {
        // ---- prep_x: Abf[:, 96:256] <- [0|x bf16|0], 8 cols (16B) / thread --
        int i = b * 256 + threadIdx.x;               // over N_PAD * 20
        if (i >= PREPX_CHUNKS) return;
        int node = i / 20;
        int c8 = i - node * 20;
        int col = 96 + c8 * 8;                       // 96..248, step 8
        ushort8 o = (ushort8){0, 0, 0, 0, 0, 0, 0, 0};
        if (node < N_NODES && col >= XOFF && col < XOFF + F_IN) {
            const float* xp = x + (size_t)node * F_IN + (col - XOFF);
            if (col <= 220) {                        // fully inside x
                float4 v0 = *(const float4*)xp;
                float4 v1 = *(const float4*)(xp + 4);
                o = (ushort8){f2bf(v0.x), f2bf(v0.y), f2bf(v0.z), f2bf(v0.w),
                              f2bf(v1.x), f2bf(v1.y), f2bf(v1.z), f2bf(v1.w)};
            } else {                                 // col==224: feats 96..99
                float4 v0 = *(const float4*)xp;
                o = (ushort8){f2bf(v0.x), f2bf(v0.y), f2bf(v0.z), f2bf(v0.w),
                              0, 0, 0, 0};
            }
        }
        // cols 96-99 of real nodes are overwritten later by spmm1 (writes 0-99)
        *(ushort8*)(Abf + (size_t)node * KA + col) = o;
        return;
    }
    b -= PREPX_BLOCKS;
    if (b < PADZ_BLOCKS) {
        // ---- pad_zero: zero pad-node rows of Abf (cols 0..255, 16B chunks) --
        int i = b * 256 + threadIdx.x;               // over 32 * 32
        if (i >= (N_PAD - N_NODES) * (KA / 8)) return;
        ((ushort8*)(Abf + (size_t)N_NODES * KA))[i] = (ushort8){0,0,0,0,0,0,0,0};
        return;
    }
    b -= PADZ_BLOCKS;
    if (b < PREPW_BLOCKS) {
        // ---- prep_w: weights/bias, bf16, with row interleave ----
        // storage row s -> jorig = (s & ~31) + 2*(s&15) + ((s>>4)&1)
        int tid = b * 256 + threadIdx.x;
        int stride = PREPW_BLOCKS * 256;
        for (int i = tid; i < HID * KA; i += stride) {   // W1: [128][256]
            int s = i >> 8, k = i & 255;
            int j = (s & ~31) + 2 * (s & 15) + ((s >> 4) & 1);
            float v = 0.f;
            if (k < F_IN) v = Wl1[j * F_IN + k];
            else if (k >= XOFF && k < XOFF + F_IN) v = Wr1[j * F_IN + (k - XOFF)];
            W1[i] = f2bf(v);
        }
        for (int i = tid; i < HID * HID; i += stride) {  // W2: [128][128]
            int s = i >> 7, k = i & 127;
            int j = (s & ~31) + 2 * (s & 15) + ((s >> 4) & 1);
            float v = (j < NCLS) ? Wl2[j * HID + k] : Wr2[(j - NCLS) * HID + k];
            W2[i] = f2bf(v);
        }
        if (tid < HID) b1[tid] = bl1[tid] + br1[tid];
        if (tid < NCLS) b2[tid] = bl2[tid] + br2[tid];
        return;
    }
    b -= PREPW_BLOCKS;
    {
        // ---- row_ptr via binary search over sorted rows ----
        int i = b * 256 + threadIdx.x;
        if (i > N_NODES) return;
        int lo = 0, hi = n_edges;
        while (lo < hi) {
            int mid = (lo + hi) >> 1;
            if (rows[mid] < i) lo = mid + 1; else hi = mid;
        }
        row_ptr[i] = lo;
    }
}

// ---- SpMM 1: Abf[node][0:100] = sum_e val * Abf[col][128:228], bf16 --------
// one wave per node, 8-deep gather pipeline. At the structural roofline:
// ~2 aligned 128-B lines per edge served at the random-gather line rate,
// needing ~40 waves/CU of outstanding gathers (r10: fusing into the 16-wave
// MFMA kernel halved effective gather BW — standalone is the right shape).
__global__ __launch_bounds__(256) void spmm1_kernel(
    const float* __restrict__ vals, const int* __restrict__ cols,
    const int* __restrict__ row_ptr, ushort* __restrict__ Abf) {
    int node = blockIdx.x * 4 + (threadIdx.x >> 6);
    if (node >= N_NODES) return;
    int lane = threadIdx.x & 63;
    int s = __builtin_amdgcn_readfirstlane(row_ptr[node]);
    int e = __builtin_amdgcn_readfirstlane(row_ptr[node + 1]);
    if (lane >= 50) return;                      // 50 lanes x 2 feats = 100
    const ushort* xb = Abf + XOFF + lane * 2;

    float accx[4] = {0.f, 0.f, 0.f, 0.f};
    float accy[4] = {0.f, 0.f, 0.f, 0.f};
    int i = s;
    for (; i + 8 <= e; i += 8) {
        float v[8]; unsigned u[8];
#pragma unroll
        for (int q = 0; q < 8; ++q) {
            v[q] = vals[i + q];
            u[q] = *(const unsigned*)(xb + (size_t)cols[i + q] * KA);
        }
#pragma unroll
        for (int q = 0; q < 8; ++q) {
            accx[q & 3] += v[q] * bflo(u[q]);
            accy[q & 3] += v[q] * bfhi(u[q]);
        }
    }
    if (i + 4 <= e) {
        float v[4]; unsigned u[4];
#pragma unroll
        for (int q = 0; q < 4; ++q) {
            v[q] = vals[i + q];
            u[q] = *(const unsigned*)(xb + (size_t)cols[i + q] * KA);
        }
#pragma unroll
        for (int q = 0; q < 4; ++q) {
            accx[q] += v[q] * bflo(u[q]);
            accy[q] += v[q] * bfhi(u[q]);
        }
        i += 4;
    }
    for (; i < e; ++i) {
        float v = vals[i];
        unsigned u = *(const unsigned*)(xb + (size_t)cols[i] * KA);
        accx[0] += v * bflo(u);
        accy[0] += v * bfhi(u);
    }
    float ax = (accx[0] + accx[1]) + (accx[2] + accx[3]);
    float ay = (accy[0] + accy[1]) + (accy[2] + accy[3]);
    unsigned o = ((unsigned)f2bf(ay) << 16) | (unsigned)f2bf(ax);
    *(unsigned*)(Abf + (size_t)node * KA + lane * 2) = o;
}

// ---- Fused GEMM: LDS-staged A (shared by 4 waves), KEEP-pinned W -----------
// r6/r9 known-good BODY — do NOT perturb (r2/r7: allocator spills when poked;
// r10: fusing the gather in starves gather concurrency). GRID_F=512 = exactly
// one launch wave at 2 blocks/CU, balanced 6-7 tiles/block.
__global__ __launch_bounds__(256, 2) void gemm_fused_kernel(
    const ushort* __restrict__ Abf, const ushort* __restrict__ W1,
    const ushort* __restrict__ W2, const float* __restrict__ b1,
    ushort* __restrict__ t, ushort* __restrict__ rb) {
    __shared__ char Ald[2][16384];                   // dbuf: 32 nodes x 256 bf16
    __shared__ char h_lds[2][8192];                  // dbuf: 32 nodes x 128 bf16
    __shared__ __align__(16) float part[2][32][4];   // [buf][node][wave] L1 partials
    int lane = threadIdx.x & 63;
    int w = threadIdx.x >> 6;
    int m = lane & 15, g = lane >> 4;

    int bb = blockIdx.x;
    int t0 = bb * TILE_Q + (bb < TILE_R ? bb : TILE_R);
    int ntl = TILE_Q + (bb < TILE_R ? 1 : 0);        // 6 or 7 tiles, balanced

    // ---- W frags: loaded once, pinned ----
    bf16x8 wf1[2][8];
    bf16x8 wf2[2][4];
#pragma unroll
    for (int o = 0; o < 2; ++o) {
        const ushort* wrow = W1 + (size_t)(w * 32 + o * 16 + m) * KA + g * 8;
#pragma unroll
        for (int kb = 0; kb < 8; ++kb) wf1[o][kb] = *(const bf16x8*)(wrow + kb * 32);
    }
#pragma unroll
    for (int o = 0; o < 2; ++o) {
        const ushort* wrow = W2 + (size_t)(w * 32 + o * 16 + m) * HID + g * 8;
#pragma unroll
        for (int kb = 0; kb < 4; ++kb) wf2[o][kb] = *(const bf16x8*)(wrow + kb * 32);
    }
#pragma unroll
    for (int o = 0; o < 2; ++o) {
#pragma unroll
        for (int kb = 0; kb < 8; ++kb) KEEP(wf1[o][kb]);
#pragma unroll
        for (int kb = 0; kb < 4; ++kb) KEEP(wf2[o][kb]);
    }
    float bias0 = b1[w * 32 + 2 * m + 0];
    float bias1 = b1[w * 32 + 2 * m + 1];

    // ---- prologue: stage tile t0 into Ald[0] ----
    bf16x8 st[4];
#pragma unroll
    for (int i = 0; i < 4; ++i)
        st[i] = *(const bf16x8*)(Abf + (size_t)t0 * 8192 + ((w * 4 + i) * 64 + lane) * 8);
#pragma unroll
    for (int i = 0; i < 4; ++i) {
        int r = w * 4 + i;
        int nl = r * 2 + (lane >> 5);
        int dst = nl * 512 + ((((lane & 31) ^ (nl & 7))) << 4);
        *(bf16x8*)(&Ald[0][0] + dst) = st[i];
    }
    __syncthreads();

    for (int j = 0; ; ) {
        int buf = j & 1;
        int base = (t0 + j) * 32;
        bool last = (j + 1 >= ntl);

        // ---- issue next tile's global loads (hide under phase 1) ----
        if (!last) {
#pragma unroll
            for (int i = 0; i < 4; ++i)
                st[i] = *(const bf16x8*)(Abf + (size_t)(t0 + j + 1) * 8192 +
                                         ((w * 4 + i) * 64 + lane) * 8);
        }

        // ---- phase 1: layer-1 MFMAs, A from LDS (swizzled reads) ----
        f32x4 acc1[2][2];
#pragma unroll
        for (int mt = 0; mt < 2; ++mt)
#pragma unroll
            for (int o = 0; o < 2; ++o) acc1[mt][o] = (f32x4){0.f, 0.f, 0.f, 0.f};
#pragma unroll
        for (int mt = 0; mt < 2; ++mt) {
            int nl = mt * 16 + m;
            int rowb = nl * 512;
            int swz = (nl & 7) << 4;
#pragma unroll
            for (int kb = 0; kb < 8; ++kb) {
                bf16x8 a = *(const bf16x8*)(&Ald[buf][0] + rowb + ((((g + 4 * kb)) << 4) ^ swz));
                acc1[mt][0] = __builtin_amdgcn_mfma_f32_16x16x32_bf16(a, wf1[0][kb], acc1[mt][0], 0, 0, 0);
                acc1[mt][1] = __builtin_amdgcn_mfma_f32_16x16x32_bf16(a, wf1[1][kb], acc1[mt][1], 0, 0, 0);
            }
        }

        // ---- write next A-tile into the other LDS buffer ----
        if (!last) {
#pragma unroll
            for (int i = 0; i < 4; ++i) {
                int r = w * 4 + i;
                int nl = r * 2 + (lane >> 5);
                int dst = nl * 512 + ((((lane & 31) ^ (nl & 7))) << 4);
                *(bf16x8*)(&Ald[buf ^ 1][0] + dst) = st[i];
            }
        }

        // ---- bias; relu(h) -> h_lds (UN-normalized); partial L1 ----
        float sr[2][4];
#pragma unroll
        for (int mt = 0; mt < 2; ++mt)
#pragma unroll
            for (int r = 0; r < 4; ++r) {
                acc1[mt][0][r] += bias0;
                acc1[mt][1][r] += bias1;
                sr[mt][r] = fabsf(acc1[mt][0][r]) + fabsf(acc1[mt][1][r]);
                int nl = mt * 16 + g * 4 + r;
                unsigned lo = f2bf(fmaxf(acc1[mt][0][r], 0.f));
                unsigned hi = f2bf(fmaxf(acc1[mt][1][r], 0.f));
                int off = (nl * 256 + w * 64 + m * 4) ^ ((nl & 7) << 4);
                *(unsigned*)(&h_lds[buf][0] + off) = (hi << 16) | lo;
            }
#pragma unroll
        for (int off = 1; off < 16; off <<= 1)
#pragma unroll
            for (int mt = 0; mt < 2; ++mt)
#pragma unroll
                for (int r = 0; r < 4; ++r) sr[mt][r] += __shfl_xor(sr[mt][r], off);
        if (m == 0) {
#pragma unroll
            for (int mt = 0; mt < 2; ++mt)
#pragma unroll
                for (int r = 0; r < 4; ++r) part[buf][mt * 16 + g * 4 + r][w] = sr[mt][r];
        }
        __syncthreads();        // single barrier/tile: h+part+next-A visible

        // ---- phase 2: layer-2 MFMAs from LDS relu(h) ----
        f32x4 acc2[2][2];
#pragma unroll
        for (int mt = 0; mt < 2; ++mt)
#pragma unroll
            for (int o = 0; o < 2; ++o) acc2[mt][o] = (f32x4){0.f, 0.f, 0.f, 0.f};
#pragma unroll
        for (int mt = 0; mt < 2; ++mt) {
            int nl = mt * 16 + m;
            bf16x8 a[4];
#pragma unroll
            for (int kb = 0; kb < 4; ++kb) {
                int off = (nl * 256 + g * 16 + kb * 64) ^ ((nl & 7) << 4);
                a[kb] = *(const bf16x8*)(&h_lds[buf][0] + off);
            }
#pragma unroll
            for (int kb = 0; kb < 4; ++kb) {
                acc2[mt][0] = __builtin_amdgcn_mfma_f32_16x16x32_bf16(a[kb], wf2[0][kb], acc2[mt][0], 0, 0, 0);
                acc2[mt][1] = __builtin_amdgcn_mfma_f32_16x16x32_bf16(a[kb], wf2[1][kb], acc2[mt][1], 0, 0, 0);
            }
        }

        // ---- epilogue: deferred 1/||h||_1, packed dword stores ----
        ushort* obuf = (w < 2) ? t : rb;
        int colb = (w & 1) * 32 + 2 * m;
#pragma unroll
        for (int mt = 0; mt < 2; ++mt)
#pragma unroll
            for (int r = 0; r < 4; ++r) {
                int nl = mt * 16 + g * 4 + r;
                int node = base + nl;
                float4 p = *(const float4*)&part[buf][nl][0];
                float inv = 1.f / fmaxf((p.x + p.y) + (p.z + p.w), 1e-12f);
                unsigned lo = f2bf(acc2[mt][0][r] * inv);
                unsigned hi = f2bf(acc2[mt][1][r] * inv);
                *(unsigned*)(obuf + (size_t)node * NCLS + colb) = (hi << 16) | lo;
            }

        if (last) break;
        ++j;
    }
}

// ---- SpMM 2 on t (bf16, D=64) + rb + bias, fused log_softmax ---------------
// one wave per node, 8-deep gather pipeline (structural roofline: 1 coalesced
// line/edge). rb/b2 tail loads hoisted ahead of the edge loop (KEEP, r8: -2.4us).
__global__ __launch_bounds__(256) void spmm2_kernel(
    const float* __restrict__ vals, const int* __restrict__ cols,
    const int* __restrict__ row_ptr, const ushort* __restrict__ t,
    const ushort* __restrict__ rb, const float* __restrict__ b2,
    float* __restrict__ out) {
    int node = blockIdx.x * 4 + (threadIdx.x >> 6);
    if (node >= N_NODES) return;
    int lane = threadIdx.x & 63;
    int s = __builtin_amdgcn_readfirstlane(row_ptr[node]);
    int e = __builtin_amdgcn_readfirstlane(row_ptr[node + 1]);

    // hoisted epilogue loads (issued before the gather loop)
    unsigned rbv = rb[(size_t)node * NCLS + lane];
    float b2v = b2[lane];
    KEEP(rbv);
    KEEP(b2v);

    float a4[4] = {0.f, 0.f, 0.f, 0.f};
    int i = s;
    for (; i + 8 <= e; i += 8) {
        float v[8], tv[8];
#pragma unroll
        for (int q = 0; q < 8; ++q) {
            v[q] = vals[i + q];
            tv[q] = bf2f(t[(size_t)cols[i + q] * NCLS + lane]);
        }
#pragma unroll
        for (int q = 0; q < 8; ++q) a4[q & 3] += v[q] * tv[q];
    }
    if (i + 4 <= e) {
        float v[4], tv[4];
#pragma unroll
        for (int q = 0; q < 4; ++q) {
            v[q] = vals[i + q];
            tv[q] = bf2f(t[(size_t)cols[i + q] * NCLS + lane]);
        }
#pragma unroll
        for (int q = 0; q < 4; ++q) a4[q] += v[q] * tv[q];
        i += 4;
    }
    for (; i < e; ++i) a4[0] += vals[i] * bf2f(t[(size_t)cols[i] * NCLS + lane]);
    float acc = (a4[0] + a4[1]) + (a4[2] + a4[3]);
    acc += bf2f((ushort)rbv) + b2v;

    float mx = acc;
#pragma unroll
    for (int off = 32; off; off >>= 1) mx = fmaxf(mx, __shfl_xor(mx, off));
    float ex = expf(acc - mx);
    float ss = ex;
#pragma unroll
    for (int off = 32; off; off >>= 1) ss += __shfl_xor(ss, off);
    out[(size_t)node * NCLS + lane] = acc - mx - logf(ss);
}

extern "C" void kernel_launch(void* const* d_in, const int* in_sizes, int n_in,
                              void* d_out, int out_size, void* d_ws, size_t ws_size,
                              hipStream_t stream) {
    const float* x         = (const float*)d_in[0];
    const float* edge_vals = (const float*)d_in[1];
    const float* Wl1       = (const float*)d_in[2];
    const float* bl1       = (const float*)d_in[3];
    const float* Wr1       = (const float*)d_in[4];
    const float* br1       = (const float*)d_in[5];
    const float* Wl2       = (const float*)d_in[6];
    const float* bl2       = (const float*)d_in[7];
    const float* Wr2       = (const float*)d_in[8];
    const float* br2       = (const float*)d_in[9];
    const int* edge_rows   = (const int*)d_in[10];
    const int* edge_cols   = (const int*)d_in[11];
    float* out = (float*)d_out;

    int n_edges = in_sizes[1];

    char* ws = (char*)d_ws;
    int*    row_ptr = (int*)(ws + 0);                        // 400 KB
    ushort* Abf     = (ushort*)(ws + (1u << 20));            // N_PAD*256*2 = 51.2 MB
    ushort* t_buf   = (ushort*)(ws + 52264960u);             // N_PAD*64*2 = 12.8 MB
    ushort* r_buf   = (ushort*)(ws + 65069056u);             // 12.8 MB
    ushort* W1      = (ushort*)(ws + 77873152u);             // 64 KB
    ushort* W2      = (ushort*)(ws + 77938688u);             // 32 KB
    float*  b1      = (float*)(ws + 77971456u);              // 512 B
    float*  b2      = (float*)(ws + 77971968u);              // 256 B

    prep_all_kernel<<<PREP_GRID, 256, 0, stream>>>(
        x, edge_rows, n_edges, Wl1, bl1, Wr1, br1, Wl2, bl2, Wr2, br2,
        Abf, W1, W2, b1, b2, row_ptr);
    spmm1_kernel<<<(N_NODES + 3) / 4, 256, 0, stream>>>(
        edge_vals, edge_cols, row_ptr, Abf);
    gemm_fused_kernel<<<GRID_F, 256, 0, stream>>>(Abf, W1, W2, b1, t_buf, r_buf);
    spmm2_kernel<<<(N_NODES + 3) / 4, 256, 0, stream>>>(
        edge_vals, edge_cols, row_ptr, t_buf, r_buf, b2, out);
}